// Round 2
// baseline (898.951 us; speedup 1.0000x reference)
//
#include <hip/hip_runtime.h>

typedef unsigned short u16;
typedef __bf16 bf16x8 __attribute__((ext_vector_type(8)));
typedef float f32x4 __attribute__((ext_vector_type(4)));

// Problem constants: B=8, N=2048, DH=512
#define SEQN 2048
#define DHID 512

static __device__ __forceinline__ float bf2f(u16 u) {
    union { unsigned int i; float f; } c; c.i = ((unsigned int)u) << 16; return c.f;
}
static __device__ __forceinline__ u16 f2bf(float f) {
    union { float f; unsigned int i; } c; c.f = f;
    unsigned int x = c.i;
    return (u16)((x + 0x7fffu + ((x >> 16) & 1u)) >> 16);
}

// ---------------------------------------------------------------------------
// fp32 -> bf16 conversion (n multiple of 8)
// ---------------------------------------------------------------------------
__global__ __launch_bounds__(256) void cvt_kernel(const float* __restrict__ src,
                                                  u16* __restrict__ dst, int n) {
    int i = (blockIdx.x * 256 + threadIdx.x) * 8;
    if (i >= n) return;
    float4 a = *(const float4*)(src + i);
    float4 b = *(const float4*)(src + i + 4);
    union { uint4 u; u16 s[8]; } o;
    o.s[0] = f2bf(a.x); o.s[1] = f2bf(a.y); o.s[2] = f2bf(a.z); o.s[3] = f2bf(a.w);
    o.s[4] = f2bf(b.x); o.s[5] = f2bf(b.y); o.s[6] = f2bf(b.z); o.s[7] = f2bf(b.w);
    *(uint4*)(dst + i) = o.u;
}

// ---------------------------------------------------------------------------
// hop_emb row means (fp32 in): hm[j] = mean_d hop_emb[j][d]
// ---------------------------------------------------------------------------
__global__ void hmean_kernel(const float* __restrict__ hop, float* __restrict__ hm) {
    int j = blockIdx.x, t = threadIdx.x;           // 64 threads
    const float* p = hop + (size_t)j * DHID + t * 8;
    float4 a = *(const float4*)p;
    float4 b = *(const float4*)(p + 4);
    float s = a.x + a.y + a.z + a.w + b.x + b.y + b.z + b.w;
#pragma unroll
    for (int m = 1; m < 64; m <<= 1) s += __shfl_xor(s, m);
    if (t == 0) hm[j] = s * (1.0f / (float)DHID);
}

// ---------------------------------------------------------------------------
// Generic bf16 MFMA GEMM: C[M,N] = A[M,K] * B + epilogue  (A,B,C bf16)
//   BT=true : B given as Bt[N,K] row-major (B^T)  -> scores = Q*K^T
//   BT=false: B given as B[K,N] row-major (weights, V)
// Tile 128x128x32, 256 threads (4 waves as 2x2 of 64x64), 16x16x32 MFMA.
// bias/adj are fp32 (original inputs).
// ---------------------------------------------------------------------------
enum { EPI_BIAS = 0, EPI_RELU = 1, EPI_SCORES = 2, EPI_PLAIN = 3 };

template <int EPI, bool BT>
__global__ __launch_bounds__(256) void gemm_k(
    const u16* __restrict__ A, const u16* __restrict__ B, u16* __restrict__ C,
    const float* __restrict__ bias, const float* __restrict__ adj,
    const float* __restrict__ hmean,
    int K, int lda, int ldb, int ldc,
    long sA, long sB, long sC, long sAdj, float scale)
{
    __shared__ u16 As[128 * 40];   // stride 40 (80B): 16B-aligned rows
    __shared__ u16 Bs[128 * 40];   // Bs[n][k]

    const int tid = threadIdx.x;
    const int bz = blockIdx.z;
    A += (size_t)bz * sA;
    B += (size_t)bz * sB;
    C += (size_t)bz * sC;
    const float* adjb = (EPI == EPI_SCORES) ? (adj + (size_t)bz * sAdj) : nullptr;

    const int bm0 = blockIdx.y * 128, bn0 = blockIdx.x * 128;
    const int wid = tid >> 6, lane = tid & 63, quad = lane >> 4, l16 = lane & 15;
    const int wm = (wid >> 1) * 64, wn = (wid & 1) * 64;

    f32x4 acc[4][4];
#pragma unroll
    for (int i = 0; i < 4; ++i)
#pragma unroll
        for (int j = 0; j < 4; ++j) acc[i][j] = (f32x4){0.f, 0.f, 0.f, 0.f};

    for (int k0 = 0; k0 < K; k0 += 32) {
        // ---- stage A tile [128 x 32] ----
#pragma unroll
        for (int it = 0; it < 2; ++it) {
            int idx = it * 256 + tid;            // chunks of 8 bf16
            int r = idx >> 2, ko = (idx & 3) << 3;
            *(uint4*)&As[r * 40 + ko] =
                *(const uint4*)(A + (size_t)(bm0 + r) * lda + k0 + ko);
        }
        // ---- stage B tile as Bs[n][k] ----
        if constexpr (BT) {
#pragma unroll
            for (int it = 0; it < 2; ++it) {
                int idx = it * 256 + tid;
                int r = idx >> 2, ko = (idx & 3) << 3;
                *(uint4*)&Bs[r * 40 + ko] =
                    *(const uint4*)(B + (size_t)(bn0 + r) * ldb + k0 + ko);
            }
        } else {
#pragma unroll
            for (int it = 0; it < 4; ++it) {
                int idx = it * 256 + tid;        // chunks of 4 bf16 along n
                int kk = idx >> 5, n4 = (idx & 31) << 2;
                union { uint2 u; u16 s[4]; } tmp;
                tmp.u = *(const uint2*)(B + (size_t)(k0 + kk) * ldb + bn0 + n4);
                Bs[(n4 + 0) * 40 + kk] = tmp.s[0];
                Bs[(n4 + 1) * 40 + kk] = tmp.s[1];
                Bs[(n4 + 2) * 40 + kk] = tmp.s[2];
                Bs[(n4 + 3) * 40 + kk] = tmp.s[3];
            }
        }
        __syncthreads();

        bf16x8 af[4], bfr[4];
#pragma unroll
        for (int i = 0; i < 4; ++i)
            af[i] = *(const bf16x8*)&As[(wm + i * 16 + l16) * 40 + quad * 8];
#pragma unroll
        for (int j = 0; j < 4; ++j)
            bfr[j] = *(const bf16x8*)&Bs[(wn + j * 16 + l16) * 40 + quad * 8];
#pragma unroll
        for (int i = 0; i < 4; ++i)
#pragma unroll
            for (int j = 0; j < 4; ++j)
                acc[i][j] = __builtin_amdgcn_mfma_f32_16x16x32_bf16(af[i], bfr[j], acc[i][j], 0, 0, 0);
        __syncthreads();
    }

    // ---- epilogue: C/D layout col=lane&15, row=quad*4+reg ----
#pragma unroll
    for (int i = 0; i < 4; ++i) {
#pragma unroll
        for (int j = 0; j < 4; ++j) {
            int gn = bn0 + wn + j * 16 + l16;
#pragma unroll
            for (int r = 0; r < 4; ++r) {
                int gm = bm0 + wm + i * 16 + quad * 4 + r;
                float v = acc[i][j][r];
                if constexpr (EPI == EPI_BIAS || EPI == EPI_RELU) v += bias[gn];
                if constexpr (EPI == EPI_RELU) v = fmaxf(v, 0.f);
                if constexpr (EPI == EPI_SCORES)
                    v = v * scale * adjb[(size_t)gm * ldc + gn] * hmean[gn];
                C[(size_t)gm * ldc + gn] = f2bf(v);
            }
        }
    }
}

// ---------------------------------------------------------------------------
// In-place softmax over rows of S [rows, 2048] (bf16)
// ---------------------------------------------------------------------------
__global__ __launch_bounds__(256) void softmax_kernel(u16* __restrict__ S) {
    size_t row = blockIdx.x;
    u16* p = S + row * (size_t)SEQN;
    int t = threadIdx.x, wid = t >> 6, lane = t & 63;

    union { uint4 u; u16 s[8]; } d;
    d.u = *(const uint4*)(p + t * 8);
    float v[8];
    float mx = -1e30f;
#pragma unroll
    for (int i = 0; i < 8; ++i) { v[i] = bf2f(d.s[i]); mx = fmaxf(mx, v[i]); }
#pragma unroll
    for (int m = 1; m < 64; m <<= 1) mx = fmaxf(mx, __shfl_xor(mx, m));
    __shared__ float redm[4], reds[4];
    if (lane == 0) redm[wid] = mx;
    __syncthreads();
    mx = fmaxf(fmaxf(redm[0], redm[1]), fmaxf(redm[2], redm[3]));

    float s = 0.f;
#pragma unroll
    for (int i = 0; i < 8; ++i) { v[i] = __expf(v[i] - mx); s += v[i]; }
#pragma unroll
    for (int m = 1; m < 64; m <<= 1) s += __shfl_xor(s, m);
    if (lane == 0) reds[wid] = s;
    __syncthreads();
    s = reds[0] + reds[1] + reds[2] + reds[3];
    float inv = 1.f / s;
#pragma unroll
    for (int i = 0; i < 8; ++i) d.s[i] = f2bf(v[i] * inv);
    *(uint4*)(p + t * 8) = d.u;
}

// ---------------------------------------------------------------------------
// LayerNorm over last dim (512): out = LN(a + b) * g + be
//   a: bf16;  b: fp32 if B_F32 else bf16;  g,be fp32; out fp32 if OUT_F32 else bf16
// ---------------------------------------------------------------------------
template <bool B_F32, bool OUT_F32>
__global__ __launch_bounds__(256) void ln_kernel(
    const u16* __restrict__ a, const void* __restrict__ bp,
    const float* __restrict__ g, const float* __restrict__ be,
    void* __restrict__ out)
{
    size_t row = blockIdx.x;
    int t = threadIdx.x, wid = t >> 6, lane = t & 63;
    const u16* pa = a + row * (size_t)DHID;

    unsigned int va = *(const unsigned int*)(pa + t * 2);
    float b0, b1;
    if constexpr (B_F32) {
        float2 vb = *(const float2*)((const float*)bp + row * (size_t)DHID + t * 2);
        b0 = vb.x; b1 = vb.y;
    } else {
        unsigned int vb = *(const unsigned int*)((const u16*)bp + row * (size_t)DHID + t * 2);
        b0 = bf2f((u16)(vb & 0xffff)); b1 = bf2f((u16)(vb >> 16));
    }
    float x0 = bf2f((u16)(va & 0xffff)) + b0;
    float x1 = bf2f((u16)(va >> 16)) + b1;
    float s = x0 + x1, sq = x0 * x0 + x1 * x1;
#pragma unroll
    for (int m = 1; m < 64; m <<= 1) { s += __shfl_xor(s, m); sq += __shfl_xor(sq, m); }
    __shared__ float rs[4], rq[4];
    if (lane == 0) { rs[wid] = s; rq[wid] = sq; }
    __syncthreads();
    s = rs[0] + rs[1] + rs[2] + rs[3];
    sq = rq[0] + rq[1] + rq[2] + rq[3];
    float mean = s * (1.f / (float)DHID);
    float var = sq * (1.f / (float)DHID) - mean * mean;
    float rstd = rsqrtf(var + 1e-5f);

    float2 vg = *(const float2*)(g + t * 2);
    float2 vbe = *(const float2*)(be + t * 2);
    float y0 = (x0 - mean) * rstd * vg.x + vbe.x;
    float y1 = (x1 - mean) * rstd * vg.y + vbe.y;
    if constexpr (OUT_F32) {
        *(float2*)((float*)out + row * (size_t)DHID + t * 2) = make_float2(y0, y1);
    } else {
        unsigned int o = (unsigned int)f2bf(y0) | ((unsigned int)f2bf(y1) << 16);
        *(unsigned int*)((u16*)out + row * (size_t)DHID + t * 2) = o;
    }
}

// ---------------------------------------------------------------------------
extern "C" void kernel_launch(void* const* d_in, const int* in_sizes, int n_in,
                              void* d_out, int out_size, void* d_ws, size_t ws_size,
                              hipStream_t stream) {
    const float* H   = (const float*)d_in[0];
    const float* adj = (const float*)d_in[1];
    const float* hop = (const float*)d_in[2];
    const float* Wq  = (const float*)d_in[3];
    const float* bq  = (const float*)d_in[4];
    const float* Wk  = (const float*)d_in[5];
    const float* bk  = (const float*)d_in[6];
    const float* Wv  = (const float*)d_in[7];
    const float* bv  = (const float*)d_in[8];
    const float* W1  = (const float*)d_in[9];
    const float* b1  = (const float*)d_in[10];
    const float* W2  = (const float*)d_in[11];
    const float* b2  = (const float*)d_in[12];
    const float* g1  = (const float*)d_in[13];
    const float* be1 = (const float*)d_in[14];
    const float* g2  = (const float*)d_in[15];
    const float* be2 = (const float*)d_in[16];

    const size_t MiB = 1ull << 20;
    char* w = (char*)d_ws;
    float* hm = (float*)w;                       // 8 KB
    u16* Hb  = (u16*)(w + 1 * MiB);              // 16 MiB
    u16* Wqb = (u16*)(w + 17 * MiB);             // 0.5 MiB
    u16* Wkb = (u16*)(w + 17 * MiB + 512 * 1024);
    u16* Wvb = (u16*)(w + 18 * MiB);
    u16* W1b = (u16*)(w + 18 * MiB + 512 * 1024);// 1 MiB
    u16* W2b = (u16*)(w + 19 * MiB + 512 * 1024);// 1 MiB
    u16* Q   = (u16*)(w + 21 * MiB);             // 16 MiB
    u16* Km  = (u16*)(w + 37 * MiB);             // 16 MiB
    u16* V   = (u16*)(w + 53 * MiB);             // 16 MiB
    u16* S4  = (u16*)(w + 69 * MiB);             // 32 MiB (4 batches) -> 101 MiB total
    // aliases (lifetimes disjoint):
    u16* AO  = Q;    // attn_out    (Q_b dead after its scores group)
    u16* X   = Km;   // LN1 output  (K dead after scores)
    u16* F2  = V;    // ffn2 output (V dead after attn_out)
    u16* HID = S4;   // ffn hidden  (S4 dead after attn_out) - 32 MiB exactly

    const int BN = 8, N = SEQN, D = DHID;
    const long nd = (long)N * D, nn = (long)N * N;
    const float scale = 0.044194173824159216f;   // 1/sqrt(512)

    // fp32 -> bf16 conversions
    cvt_kernel<<<(BN * N * D) / (8 * 256), 256, 0, stream>>>(H, Hb, BN * N * D);
    cvt_kernel<<<(D * D) / (8 * 256), 256, 0, stream>>>(Wq, Wqb, D * D);
    cvt_kernel<<<(D * D) / (8 * 256), 256, 0, stream>>>(Wk, Wkb, D * D);
    cvt_kernel<<<(D * D) / (8 * 256), 256, 0, stream>>>(Wv, Wvb, D * D);
    cvt_kernel<<<(D * 2 * D) / (8 * 256), 256, 0, stream>>>(W1, W1b, D * 2 * D);
    cvt_kernel<<<(2 * D * D) / (8 * 256), 256, 0, stream>>>(W2, W2b, 2 * D * D);

    hmean_kernel<<<N, 64, 0, stream>>>(hop, hm);

    // Q,K,V = H @ W + b    [B*N, 512] x [512, 512]
    gemm_k<EPI_BIAS, false><<<dim3(4, 128, 1), 256, 0, stream>>>(
        Hb, Wqb, Q, bq, nullptr, nullptr, D, D, D, D, 0, 0, 0, 0, 0.f);
    gemm_k<EPI_BIAS, false><<<dim3(4, 128, 1), 256, 0, stream>>>(
        Hb, Wkb, Km, bk, nullptr, nullptr, D, D, D, D, 0, 0, 0, 0, 0.f);
    gemm_k<EPI_BIAS, false><<<dim3(4, 128, 1), 256, 0, stream>>>(
        Hb, Wvb, V, bv, nullptr, nullptr, D, D, D, D, 0, 0, 0, 0, 0.f);

    // attention in 2 groups of 4 batches (keeps S at 32 MiB)
    for (int g = 0; g < 2; ++g) {
        const u16* Qg = Q + (size_t)g * 4 * nd;
        const u16* Kg = Km + (size_t)g * 4 * nd;
        const u16* Vg = V + (size_t)g * 4 * nd;
        const float* adjg = adj + (size_t)g * 4 * nn;
        u16* AOg = AO + (size_t)g * 4 * nd;

        // S = (Q K^T / sqrt(d)) * adj * hmean[j]
        gemm_k<EPI_SCORES, true><<<dim3(16, 16, 4), 256, 0, stream>>>(
            Qg, Kg, S4, nullptr, adjg, hm, D, D, D, N, nd, nd, nn, nn, scale);

        softmax_kernel<<<4 * N, 256, 0, stream>>>(S4);

        // attn_out = P @ V    [2048,2048] x [2048,512]
        gemm_k<EPI_PLAIN, false><<<dim3(4, 16, 4), 256, 0, stream>>>(
            S4, Vg, AOg, nullptr, nullptr, nullptr, N, N, D, D, nn, nd, nd, 0, 0.f);
    }

    // x = LN(attn_out + H)   (H fp32)
    ln_kernel<true, false><<<BN * N, 256, 0, stream>>>(AO, H, g1, be1, X);

    // hid = relu(x @ W1 + b1)   [B*N,512] x [512,1024]
    gemm_k<EPI_RELU, false><<<dim3(8, 128, 1), 256, 0, stream>>>(
        X, W1b, HID, b1, nullptr, nullptr, D, D, 2 * D, 2 * D, 0, 0, 0, 0, 0.f);

    // f2 = hid @ W2 + b2        [B*N,1024] x [1024,512]
    gemm_k<EPI_BIAS, false><<<dim3(4, 128, 1), 256, 0, stream>>>(
        HID, W2b, F2, b2, nullptr, nullptr, 2 * D, 2 * D, D, D, 0, 0, 0, 0, 0.f);

    // out = LN(f2 + x)  -> fp32 d_out
    ln_kernel<false, true><<<BN * N, 256, 0, stream>>>(F2, X, g2, be2, (float*)d_out);
}

// Round 3
// 589.614 us; speedup vs baseline: 1.5246x; 1.5246x over previous
//
#include <hip/hip_runtime.h>

typedef unsigned short u16;
typedef __bf16 bf16x8 __attribute__((ext_vector_type(8)));
typedef float f32x4 __attribute__((ext_vector_type(4)));

// Problem constants: B=8, N=2048, DH=512
#define SEQN 2048
#define DHID 512

static __device__ __forceinline__ float bf2f(u16 u) {
    union { unsigned int i; float f; } c; c.i = ((unsigned int)u) << 16; return c.f;
}
static __device__ __forceinline__ u16 f2bf(float f) {
    union { float f; unsigned int i; } c; c.f = f;
    unsigned int x = c.i;
    return (u16)((x + 0x7fffu + ((x >> 16) & 1u)) >> 16);
}

// async global->LDS, 16B per lane, LDS dest = wave-uniform base + lane*16
static __device__ __forceinline__ void gld_lds16(const u16* g, u16* l) {
    __builtin_amdgcn_global_load_lds(
        (__attribute__((address_space(1))) void*)(g),
        (__attribute__((address_space(3))) void*)(l), 16, 0, 0);
}

// ---------------------------------------------------------------------------
// fp32 -> bf16 conversion (n multiple of 8)
// ---------------------------------------------------------------------------
__global__ __launch_bounds__(256) void cvt_kernel(const float* __restrict__ src,
                                                  u16* __restrict__ dst, int n) {
    int i = (blockIdx.x * 256 + threadIdx.x) * 8;
    if (i >= n) return;
    float4 a = *(const float4*)(src + i);
    float4 b = *(const float4*)(src + i + 4);
    union { uint4 u; u16 s[8]; } o;
    o.s[0] = f2bf(a.x); o.s[1] = f2bf(a.y); o.s[2] = f2bf(a.z); o.s[3] = f2bf(a.w);
    o.s[4] = f2bf(b.x); o.s[5] = f2bf(b.y); o.s[6] = f2bf(b.z); o.s[7] = f2bf(b.w);
    *(uint4*)(dst + i) = o.u;
}

// fp32 [K][N] -> bf16 transposed [N][K]
__global__ __launch_bounds__(256) void cvt_t_kernel(const float* __restrict__ src,
                                                    u16* __restrict__ dst, int K, int N) {
    int idx = blockIdx.x * 256 + threadIdx.x;
    if (idx >= K * N) return;
    int n = idx / K, k = idx - n * K;
    dst[idx] = f2bf(src[(size_t)k * N + n]);
}

// ---------------------------------------------------------------------------
// hop_emb row means (fp32 in): hm[j] = mean_d hop_emb[j][d]
// ---------------------------------------------------------------------------
__global__ void hmean_kernel(const float* __restrict__ hop, float* __restrict__ hm) {
    int j = blockIdx.x, t = threadIdx.x;           // 64 threads
    const float* p = hop + (size_t)j * DHID + t * 8;
    float4 a = *(const float4*)p;
    float4 b = *(const float4*)(p + 4);
    float s = a.x + a.y + a.z + a.w + b.x + b.y + b.z + b.w;
#pragma unroll
    for (int m = 1; m < 64; m <<= 1) s += __shfl_xor(s, m);
    if (t == 0) hm[j] = s * (1.0f / (float)DHID);
}

// ---------------------------------------------------------------------------
// BT MFMA GEMM: C[M,N] = A[M,K] * Bt[N,K]^T + epilogue  (A,Bt,C bf16)
// Tile 128x128x32, 256 threads (4 waves as 2x2 of 64x64), 16x16x32 MFMA.
// Staging via global_load_lds width=16, unpadded LDS [row][k] stride 32.
// ---------------------------------------------------------------------------
enum { EPI_BIAS = 0, EPI_RELU = 1, EPI_SCORES = 2, EPI_PLAIN = 3, EPI_BIAS_T = 4 };

template <int EPI>
__global__ __launch_bounds__(256) void gemm_bt(
    const u16* __restrict__ A, const u16* __restrict__ Bt, u16* __restrict__ C,
    const float* __restrict__ bias, const float* __restrict__ adj,
    const float* __restrict__ hmean,
    int K, int lda, int ldb, int ldc,
    long sA, long sB, long sC, long sAdj, float scale)
{
    __shared__ u16 As[128 * 32];   // 8 KB, [row][k], row stride 64 B
    __shared__ u16 Bs[128 * 32];   // 8 KB, [n][k]

    const int tid = threadIdx.x;
    const int bz = blockIdx.z;
    const u16* Ab = A + (size_t)bz * sA;
    const u16* Bb = Bt + (size_t)bz * sB;
    u16* Cb = C + (size_t)bz * sC;

    const int bm0 = blockIdx.y * 128, bn0 = blockIdx.x * 128;
    const int wid = tid >> 6, lane = tid & 63, quad = lane >> 4, l16 = lane & 15;
    const int wm = (wid >> 1) * 64, wn = (wid & 1) * 64;
    const int srow = lane >> 2;            // 0..15: row within 16-row chunk
    const int skof = (lane & 3) * 8;       // k element offset (8 bf16 = 16 B)

    f32x4 acc[4][4];
#pragma unroll
    for (int i = 0; i < 4; ++i)
#pragma unroll
        for (int j = 0; j < 4; ++j) acc[i][j] = (f32x4){0.f, 0.f, 0.f, 0.f};

    for (int k0 = 0; k0 < K; k0 += 32) {
        // ---- async stage A tile [128 x 32]: chunk c covers rows 16c..16c+15 ----
#pragma unroll
        for (int it = 0; it < 2; ++it) {
            int c = wid * 2 + it;          // wave-uniform
            gld_lds16(Ab + (size_t)(bm0 + c * 16 + srow) * lda + k0 + skof,
                      &As[c * 512]);
        }
#pragma unroll
        for (int it = 0; it < 2; ++it) {
            int c = wid * 2 + it;
            gld_lds16(Bb + (size_t)(bn0 + c * 16 + srow) * ldb + k0 + skof,
                      &Bs[c * 512]);
        }
        __syncthreads();

        bf16x8 af[4], bfr[4];
#pragma unroll
        for (int i = 0; i < 4; ++i)
            af[i] = *(const bf16x8*)&As[(wm + i * 16 + l16) * 32 + quad * 8];
#pragma unroll
        for (int j = 0; j < 4; ++j)
            bfr[j] = *(const bf16x8*)&Bs[(wn + j * 16 + l16) * 32 + quad * 8];
#pragma unroll
        for (int i = 0; i < 4; ++i)
#pragma unroll
            for (int j = 0; j < 4; ++j)
                acc[i][j] = __builtin_amdgcn_mfma_f32_16x16x32_bf16(af[i], bfr[j], acc[i][j], 0, 0, 0);
        __syncthreads();
    }

    // ---- epilogue: C/D layout col=lane&15, row=quad*4+reg ----
#pragma unroll
    for (int i = 0; i < 4; ++i) {
#pragma unroll
        for (int j = 0; j < 4; ++j) {
            const int gn = bn0 + wn + j * 16 + l16;
            const int gm0 = bm0 + wm + i * 16 + quad * 4;
            if constexpr (EPI == EPI_BIAS || EPI == EPI_RELU) {
                const float b = bias[gn];
#pragma unroll
                for (int r = 0; r < 4; ++r) {
                    float v = acc[i][j][r] + b;
                    if constexpr (EPI == EPI_RELU) v = fmaxf(v, 0.f);
                    Cb[(size_t)(gm0 + r) * ldc + gn] = f2bf(v);
                }
            } else if constexpr (EPI == EPI_SCORES) {
                const float* adjb = adj + (size_t)bz * sAdj;
                const float hmn = hmean[gn];
#pragma unroll
                for (int r = 0; r < 4; ++r) {
                    float v = acc[i][j][r] * scale * adjb[(size_t)(gm0 + r) * ldc + gn] * hmn;
                    Cb[(size_t)(gm0 + r) * ldc + gn] = f2bf(v);
                }
            } else if constexpr (EPI == EPI_BIAS_T) {
                // write transposed: Ct[b][col][row], per-batch [512][2048]
                const float b = bias[gn];
                const int bb = gm0 >> 11, n = gm0 & 2047;
                ushort4 o;
                o.x = f2bf(acc[i][j][0] + b);
                o.y = f2bf(acc[i][j][1] + b);
                o.z = f2bf(acc[i][j][2] + b);
                o.w = f2bf(acc[i][j][3] + b);
                *(ushort4*)&C[((size_t)bb * 512 + gn) * 2048 + n] = o;
            } else {
#pragma unroll
                for (int r = 0; r < 4; ++r)
                    Cb[(size_t)(gm0 + r) * ldc + gn] = f2bf(acc[i][j][r]);
            }
        }
    }
}

// ---------------------------------------------------------------------------
// In-place softmax over rows of S [rows, 2048] (bf16)
// ---------------------------------------------------------------------------
__global__ __launch_bounds__(256) void softmax_kernel(u16* __restrict__ S) {
    size_t row = blockIdx.x;
    u16* p = S + row * (size_t)SEQN;
    int t = threadIdx.x, wid = t >> 6, lane = t & 63;

    union { uint4 u; u16 s[8]; } d;
    d.u = *(const uint4*)(p + t * 8);
    float v[8];
    float mx = -1e30f;
#pragma unroll
    for (int i = 0; i < 8; ++i) { v[i] = bf2f(d.s[i]); mx = fmaxf(mx, v[i]); }
#pragma unroll
    for (int m = 1; m < 64; m <<= 1) mx = fmaxf(mx, __shfl_xor(mx, m));
    __shared__ float redm[4], reds[4];
    if (lane == 0) redm[wid] = mx;
    __syncthreads();
    mx = fmaxf(fmaxf(redm[0], redm[1]), fmaxf(redm[2], redm[3]));

    float s = 0.f;
#pragma unroll
    for (int i = 0; i < 8; ++i) { v[i] = __expf(v[i] - mx); s += v[i]; }
#pragma unroll
    for (int m = 1; m < 64; m <<= 1) s += __shfl_xor(s, m);
    if (lane == 0) reds[wid] = s;
    __syncthreads();
    s = reds[0] + reds[1] + reds[2] + reds[3];
    float inv = 1.f / s;
#pragma unroll
    for (int i = 0; i < 8; ++i) d.s[i] = f2bf(v[i] * inv);
    *(uint4*)(p + t * 8) = d.u;
}

// ---------------------------------------------------------------------------
// LayerNorm over last dim (512): out = LN(a + b) * g + be
// ---------------------------------------------------------------------------
template <bool B_F32, bool OUT_F32>
__global__ __launch_bounds__(256) void ln_kernel(
    const u16* __restrict__ a, const void* __restrict__ bp,
    const float* __restrict__ g, const float* __restrict__ be,
    void* __restrict__ out)
{
    size_t row = blockIdx.x;
    int t = threadIdx.x, wid = t >> 6, lane = t & 63;
    const u16* pa = a + row * (size_t)DHID;

    unsigned int va = *(const unsigned int*)(pa + t * 2);
    float b0, b1;
    if constexpr (B_F32) {
        float2 vb = *(const float2*)((const float*)bp + row * (size_t)DHID + t * 2);
        b0 = vb.x; b1 = vb.y;
    } else {
        unsigned int vb = *(const unsigned int*)((const u16*)bp + row * (size_t)DHID + t * 2);
        b0 = bf2f((u16)(vb & 0xffff)); b1 = bf2f((u16)(vb >> 16));
    }
    float x0 = bf2f((u16)(va & 0xffff)) + b0;
    float x1 = bf2f((u16)(va >> 16)) + b1;
    float s = x0 + x1, sq = x0 * x0 + x1 * x1;
#pragma unroll
    for (int m = 1; m < 64; m <<= 1) { s += __shfl_xor(s, m); sq += __shfl_xor(sq, m); }
    __shared__ float rs[4], rq[4];
    if (lane == 0) { rs[wid] = s; rq[wid] = sq; }
    __syncthreads();
    s = rs[0] + rs[1] + rs[2] + rs[3];
    sq = rq[0] + rq[1] + rq[2] + rq[3];
    float mean = s * (1.f / (float)DHID);
    float var = sq * (1.f / (float)DHID) - mean * mean;
    float rstd = rsqrtf(var + 1e-5f);

    float2 vg = *(const float2*)(g + t * 2);
    float2 vbe = *(const float2*)(be + t * 2);
    float y0 = (x0 - mean) * rstd * vg.x + vbe.x;
    float y1 = (x1 - mean) * rstd * vg.y + vbe.y;
    if constexpr (OUT_F32) {
        *(float2*)((float*)out + row * (size_t)DHID + t * 2) = make_float2(y0, y1);
    } else {
        unsigned int o = (unsigned int)f2bf(y0) | ((unsigned int)f2bf(y1) << 16);
        *(unsigned int*)((u16*)out + row * (size_t)DHID + t * 2) = o;
    }
}

// ---------------------------------------------------------------------------
extern "C" void kernel_launch(void* const* d_in, const int* in_sizes, int n_in,
                              void* d_out, int out_size, void* d_ws, size_t ws_size,
                              hipStream_t stream) {
    const float* H   = (const float*)d_in[0];
    const float* adj = (const float*)d_in[1];
    const float* hop = (const float*)d_in[2];
    const float* Wq  = (const float*)d_in[3];
    const float* bq  = (const float*)d_in[4];
    const float* Wk  = (const float*)d_in[5];
    const float* bk  = (const float*)d_in[6];
    const float* Wv  = (const float*)d_in[7];
    const float* bv  = (const float*)d_in[8];
    const float* W1  = (const float*)d_in[9];
    const float* b1  = (const float*)d_in[10];
    const float* W2  = (const float*)d_in[11];
    const float* b2  = (const float*)d_in[12];
    const float* g1  = (const float*)d_in[13];
    const float* be1 = (const float*)d_in[14];
    const float* g2  = (const float*)d_in[15];
    const float* be2 = (const float*)d_in[16];

    const size_t MiB = 1ull << 20;
    char* w = (char*)d_ws;
    float* hm  = (float*)w;                       // 8 KB
    u16* Hb   = (u16*)(w + 1 * MiB);              // 16 MiB
    u16* Wqt  = (u16*)(w + 17 * MiB);             // 0.5 MiB each
    u16* Wkt  = (u16*)(w + 17 * MiB + 512 * 1024);
    u16* Wvt  = (u16*)(w + 18 * MiB);
    u16* W1t  = (u16*)(w + 18 * MiB + 512 * 1024);// 1 MiB
    u16* W2t  = (u16*)(w + 19 * MiB + 512 * 1024);// 1 MiB
    u16* Q    = (u16*)(w + 21 * MiB);             // 16 MiB
    u16* Kb   = (u16*)(w + 37 * MiB);             // 16 MiB
    u16* Vt   = (u16*)(w + 53 * MiB);             // 16 MiB  [b][512][2048]
    u16* S    = (u16*)(w + 69 * MiB);             // 32 or 64 MiB
    // aliases (lifetimes disjoint):
    u16* AO  = Q;    // attn_out
    u16* X   = Kb;   // LN1 output
    u16* F2  = Vt;   // ffn2 output
    u16* HID = S;    // ffn hidden (32 MiB)

    const int BN = 8, N = SEQN, D = DHID;
    const long nd = (long)N * D, nn = (long)N * N;
    const float scale = 0.044194173824159216f;   // 1/sqrt(512)

    const int groups = (ws_size >= 133 * MiB) ? 1 : 2;
    const int gb = BN / groups;                  // batches per group

    // fp32 -> bf16 conversions (weights transposed)
    cvt_kernel<<<(BN * N * D) / (8 * 256), 256, 0, stream>>>(H, Hb, BN * N * D);
    cvt_t_kernel<<<(D * D + 255) / 256, 256, 0, stream>>>(Wq, Wqt, D, D);
    cvt_t_kernel<<<(D * D + 255) / 256, 256, 0, stream>>>(Wk, Wkt, D, D);
    cvt_t_kernel<<<(D * D + 255) / 256, 256, 0, stream>>>(Wv, Wvt, D, D);
    cvt_t_kernel<<<(D * 2 * D + 255) / 256, 256, 0, stream>>>(W1, W1t, D, 2 * D);
    cvt_t_kernel<<<(2 * D * D + 255) / 256, 256, 0, stream>>>(W2, W2t, 2 * D, D);

    hmean_kernel<<<N, 64, 0, stream>>>(hop, hm);

    // Q,K = H @ W + b ; V written transposed
    gemm_bt<EPI_BIAS><<<dim3(4, 128, 1), 256, 0, stream>>>(
        Hb, Wqt, Q, bq, nullptr, nullptr, D, D, D, D, 0, 0, 0, 0, 0.f);
    gemm_bt<EPI_BIAS><<<dim3(4, 128, 1), 256, 0, stream>>>(
        Hb, Wkt, Kb, bk, nullptr, nullptr, D, D, D, D, 0, 0, 0, 0, 0.f);
    gemm_bt<EPI_BIAS_T><<<dim3(4, 128, 1), 256, 0, stream>>>(
        Hb, Wvt, Vt, bv, nullptr, nullptr, D, D, D, D, 0, 0, 0, 0, 0.f);

    for (int g = 0; g < groups; ++g) {
        const u16* Qg = Q + (size_t)g * gb * nd;
        const u16* Kg = Kb + (size_t)g * gb * nd;
        const u16* Vg = Vt + (size_t)g * gb * nd;
        const float* adjg = adj + (size_t)g * gb * nn;
        u16* AOg = AO + (size_t)g * gb * nd;

        // S = (Q K^T / sqrt(d)) * adj * hmean[j]
        gemm_bt<EPI_SCORES><<<dim3(16, 16, gb), 256, 0, stream>>>(
            Qg, Kg, S, nullptr, adjg, hm, D, D, D, N, nd, nd, nn, nn, scale);

        softmax_kernel<<<gb * N, 256, 0, stream>>>(S);

        // attn_out = P @ V : A=S [2048,2048], Bt=Vt [512,2048]
        gemm_bt<EPI_PLAIN><<<dim3(4, 16, gb), 256, 0, stream>>>(
            S, Vg, AOg, nullptr, nullptr, nullptr, N, N, N, D, nn, nd, nd, 0, 0.f);
    }

    // x = LN(attn_out + H)   (H fp32)
    ln_kernel<true, false><<<BN * N, 256, 0, stream>>>(AO, H, g1, be1, X);

    // hid = relu(x @ W1 + b1)
    gemm_bt<EPI_RELU><<<dim3(8, 128, 1), 256, 0, stream>>>(
        X, W1t, HID, b1, nullptr, nullptr, D, D, D, 2 * D, 0, 0, 0, 0, 0.f);

    // f2 = hid @ W2 + b2
    gemm_bt<EPI_BIAS><<<dim3(4, 128, 1), 256, 0, stream>>>(
        HID, W2t, F2, b2, nullptr, nullptr, 2 * D, 2 * D, 2 * D, D, 0, 0, 0, 0, 0.f);

    // out = LN(f2 + x)  -> fp32 d_out
    ln_kernel<false, true><<<BN * N, 256, 0, stream>>>(F2, X, g2, be2, (float*)d_out);
}